// Round 1
// baseline (353.940 us; speedup 1.0000x reference)
//
#include <hip/hip_runtime.h>
#include <math.h>

// Problem constants
#define D_MODEL 2048
#define N_HEADS 16
#define N_KV    4
#define DH      128
#define QKV_DIM 3072   // 2048 + 2*4*128
#define TT      2048   // T
#define BB      2      // B
#define ROWS    (BB*TT)  // 4096

// LDS strides (u16 units)
#define VS_STRIDE 72    // 128 rows (d) x 64 kv (padded)
#define PS_STRIDE 72    // 32 rows (q) x 64 kv (padded)

typedef unsigned short u16;
typedef short short8 __attribute__((ext_vector_type(8)));
typedef short short4v __attribute__((ext_vector_type(4)));
typedef float float4v __attribute__((ext_vector_type(4)));

__device__ inline float b2f(u16 h) {
    union { unsigned u; float f; } v; v.u = ((unsigned)h) << 16; return v.f;
}
__device__ inline u16 f2b(float f) {
    union { float f; unsigned u; } v; v.f = f;
    unsigned r = v.u + 0x7FFF + ((v.u >> 16) & 1);
    return (u16)(r >> 16);
}

// async global->LDS DMA, 16 bytes/lane. LDS dest = wave-uniform base + lane*16.
__device__ inline void async16(const void* g, void* l) {
    __builtin_amdgcn_global_load_lds(
        (const __attribute__((address_space(1))) void*)g,
        (__attribute__((address_space(3))) void*)l, 16, 0, 0);
}

// ---------------------------------------------------------------------------
// fp32 -> bf16 bulk convert (vectorized)
__global__ void convert_f2b(const float* __restrict__ src, u16* __restrict__ dst) {
    int i = blockIdx.x * 256 + threadIdx.x;
    float4v a = *(const float4v*)(src + (size_t)i * 4);
    short4v p;
    p[0] = (short)f2b(a[0]); p[1] = (short)f2b(a[1]);
    p[2] = (short)f2b(a[2]); p[3] = (short)f2b(a[3]);
    *(short4v*)(dst + (size_t)i * 4) = p;
}

// ---------------------------------------------------------------------------
// 32x32 transpose + fp32->bf16: dst[c][r] = bf16(src[r][c + col0]). 256 thr.
__global__ void transpose_f2b(const float* __restrict__ src, u16* __restrict__ dst,
                              int R, int C, int col0) {
    __shared__ __align__(16) u16 tile[32][33];
    int bc = blockIdx.x * 32, br = blockIdx.y * 32;
    int tx = threadIdx.x & 31, ty = threadIdx.x >> 5;   // ty 0..7
    for (int i = ty; i < 32; i += 8)
        tile[i][tx] = f2b(src[(size_t)(br + i) * C + col0 + bc + tx]);
    __syncthreads();
    for (int i = ty; i < 32; i += 8)
        dst[(size_t)(bc + i) * R + br + tx] = tile[tx][i];
}

// ---------------------------------------------------------------------------
// m97-style async GEMM: C[M,N] = A[M,K] @ Bt[N,K]^T, bf16 in, fp32 accum.
// B^T split across two buffers at N-row `nsplit` (workspace tetris).
// ROPE: fused rotary on cols < 2560 (fast hw trig: __sinf/__cosf/__expf).
template<bool F32OUT, bool ROPE>
__global__ __launch_bounds__(256) void gemm_bt_async(
    const u16* __restrict__ A, const u16* __restrict__ Bt1, const u16* __restrict__ Bt2,
    int nsplit, void* __restrict__ Cv, int M, int N, int K, const int* __restrict__ sp) {
    __shared__ __align__(16) u16 As[128 * 32];
    __shared__ __align__(16) u16 Bs[128 * 32];
    const int tid = threadIdx.x;
    const int wave = tid >> 6, lane = tid & 63;
    const int quad = lane >> 4, l16 = lane & 15;
    const int bm = blockIdx.y * 128, bn = blockIdx.x * 128;
    const int wm = (wave >> 1) * 64, wn = (wave & 1) * 64;
    const int srow = wave * 32 + (lane >> 2);
    const int scol = (lane & 3) * 8;
    const u16* Bt = (bn < nsplit) ? (Bt1 + (size_t)bn * K)
                                  : (Bt2 + (size_t)(bn - nsplit) * K);

    float4v acc[4][4] = {};

    for (int k0 = 0; k0 < K; k0 += 32) {
        async16(A + (size_t)(bm + srow) * K + k0 + scol, (char*)As + wave * 2048);
        async16(A + (size_t)(bm + srow + 16) * K + k0 + scol, (char*)As + wave * 2048 + 1024);
        async16(Bt + (size_t)srow * K + k0 + scol, (char*)Bs + wave * 2048);
        async16(Bt + (size_t)(srow + 16) * K + k0 + scol, (char*)Bs + wave * 2048 + 1024);
        __syncthreads();
        short8 af[4], bf[4];
#pragma unroll
        for (int i = 0; i < 4; i++)
            af[i] = *(const short8*)(As + (wm + i * 16 + l16) * 32 + quad * 8);
#pragma unroll
        for (int j = 0; j < 4; j++)
            bf[j] = *(const short8*)(Bs + (wn + j * 16 + l16) * 32 + quad * 8);
#pragma unroll
        for (int i = 0; i < 4; i++)
#pragma unroll
            for (int j = 0; j < 4; j++)
                acc[i][j] = __builtin_amdgcn_mfma_f32_16x16x32_bf16(af[i], bf[j], acc[i][j], 0, 0, 0);
        __syncthreads();
    }
    const int sp0 = ROPE ? *sp : 0;
    // epilogue: C/D layout col=lane&15, row=quad*4+reg (m89/m91-verified).
#pragma unroll
    for (int j = 0; j < 4; j++) {
        int col = bn + wn + j * 16 + l16;
        bool do_rope = ROPE && (col < 2560);
        float inv = 0.f;
        if (do_rope) inv = __expf(-0.14391156816f * (float)((col & 127) >> 1));
#pragma unroll
        for (int i = 0; i < 4; i++) {
            int row0 = bm + wm + i * 16 + quad * 4;
#pragma unroll
            for (int r = 0; r < 4; r++) {
                float v = acc[i][j][r];
                if (do_rope) {
                    float partner = __shfl_xor(v, 1, 64);
                    float ang = (float)(sp0 + ((row0 + r) & (TT - 1))) * inv;
                    float c = __cosf(ang), s = __sinf(ang);
                    v = (col & 1) ? (partner * s + v * c)
                                  : (v * c - partner * s);
                }
                if (F32OUT) ((float*)Cv)[(size_t)(row0 + r) * N + col] = v;
                else        ((u16*)Cv)[(size_t)(row0 + r) * N + col] = f2b(v);
            }
        }
    }
}

// ---------------------------------------------------------------------------
// Flash attention v7: 256 threads = 4 waves, q-tile 128 rows (32/wave).
// vs v6: (a) 32 q-rows/wave halves per-work LDS read traffic (K/V fragment
// reads amortize over 2x q-rows; each K/V fragment feeds both row-groups);
// (b) balanced q-slot map qt = qq<8 ? qq : 23-qq so co-resident block pairs
// (bx, bx+256) always sum to 15 -> uniform 34 kv-tiles per CU (was 12..56).
// K staged via global_load_lds double-buffer with XOR-SWIZZLED layout:
//   LDS[row][c] = global[row][c ^ (row&7)]  (c = 8-u16 chunk index)
// XCD swizzle bx&7 -> (b,hk). Fixed-offset softmax; l via ones MFMA.
__global__ __launch_bounds__(256, 2) void attn_kernel(
    const u16* __restrict__ qkv, u16* __restrict__ y) {
    __shared__ __align__(16) u16 Ks[2][64 * 128];          // 2 x 16384 B
    __shared__ __align__(16) u16 Vs[128 * VS_STRIDE];      // 18432 B
    __shared__ __align__(16) u16 Ps[4][32 * PS_STRIDE];    // 18432 B (total 69632)

    const int tid = threadIdx.x;
    const int wave = tid >> 6, lane = tid & 63;
    const int quad = lane >> 4, l16 = lane & 15;
    const int bx = blockIdx.x;
    const int xg = bx & 7;             // XCD group = (b, hk)
    const int b = xg >> 2, hk = xg & 3;
    const int jj = bx >> 3;            // 0..63 within group
    const int h = hk * 4 + (jj & 3);
    const int qq = jj >> 2;            // 0..15
    // balanced pairing: CU gets bx and bx+256 (same h, qq and qq+8);
    // qt(qq) + qt(qq+8) == 15 for all qq -> every CU does 34 kv-tiles.
    const int qt = (qq < 8) ? qq : (23 - qq);
    const int qcol = h * 128;
    const int kcol = 2048 + hk * 128;
    const int vcol = 2560 + hk * 128;
    const float scale = 0.08838834764831845f;  // 1/sqrt(128)

    // Q fragments in registers (reused every kv-tile): 2 row-groups of 16
    const int wq0 = qt * 128 + wave * 32;
    short8 qf[2][4];
#pragma unroll
    for (int g = 0; g < 2; g++) {
        const u16* qrow = qkv + (size_t)(b * TT + wq0 + g * 16 + l16) * QKV_DIM + qcol;
#pragma unroll
        for (int d = 0; d < 4; d++)
            qf[g][d] = *(const short8*)(qrow + d * 32 + quad * 8);
    }

    // Oacc[g][0..7]: O tiles (2 x 16 x 128). Ol[g]: row-sum l via ones-column.
    float4v Oacc[2][8] = {};
    float4v Ol[2] = {};
    const short8 ONES = {(short)0x3F80, (short)0x3F80, (short)0x3F80, (short)0x3F80,
                         (short)0x3F80, (short)0x3F80, (short)0x3F80, (short)0x3F80};

    const int ktmax = 2 * qt + 1;

    // K DMA source offsets with XOR swizzle. Instruction s of wave covers LDS
    // rows wave*16 + s*4 + quad, chunk l16; source chunk = l16 ^ (row&7).
    size_t kg[4];
#pragma unroll
    for (int s = 0; s < 4; s++) {
        int rl = (s * 4 + quad) & 7;           // row&7 (wave*16 is 0 mod 8)
        kg[s] = (size_t)(wave * 16 + s * 4 + quad) * QKV_DIM
              + (size_t)((l16 ^ rl) * 8);
    }
    // kt=0 prefetch: K via DMA, V via registers
    {
        const u16* kb = qkv + (size_t)(b * TT) * QKV_DIM;
#pragma unroll
        for (int s = 0; s < 4; s++)
            async16(kb + kcol + kg[s], (char*)Ks[0] + wave * 4096 + s * 1024);
    }
    short8 vreg[4];
#pragma unroll
    for (int s = 0; s < 4; s++)
        vreg[s] = *(const short8*)(qkv + (size_t)(b * TT + lane) * QKV_DIM + vcol + (wave * 4 + s) * 8);

    for (int kt = 0; kt <= ktmax; kt++) {
        const u16* Kcur = Ks[kt & 1];
        __syncthreads();   // drains K-DMA + V prefetch; prev tile's readers done
        // commit V (transposed) to LDS: consecutive-u16 stores, conflict-free
#pragma unroll
        for (int s = 0; s < 4; s++) {
            int dgi = wave * 4 + s;
#pragma unroll
            for (int j8 = 0; j8 < 8; j8++)
                Vs[(dgi * 8 + j8) * VS_STRIDE + lane] = (u16)vreg[s][j8];
        }
        __syncthreads();   // Vs visible
        if (kt < ktmax) {  // prefetch next tile (overlaps all compute below)
            const u16* kb = qkv + (size_t)(b * TT + (kt + 1) * 64) * QKV_DIM;
#pragma unroll
            for (int s = 0; s < 4; s++)
                async16(kb + kcol + kg[s], (char*)Ks[(kt + 1) & 1] + wave * 4096 + s * 1024);
#pragma unroll
            for (int s = 0; s < 4; s++)
                vreg[s] = *(const short8*)(kb + (size_t)lane * QKV_DIM + vcol + (wave * 4 + s) * 8);
        }

        // S = Q*K^T  (K read through XOR swizzle; each K fragment feeds BOTH
        // q row-groups -> K LDS read traffic amortized over 32 q-rows)
        float4v S[2][4] = {};
#pragma unroll
        for (int d = 0; d < 4; d++) {
#pragma unroll
            for (int j = 0; j < 4; j++) {
                short8 bk = *(const short8*)(Kcur + (j * 16 + l16) * 128
                                             + (((d * 4 + quad) ^ (l16 & 7)) * 8));
#pragma unroll
                for (int g = 0; g < 2; g++)
                    S[g][j] = __builtin_amdgcn_mfma_f32_16x16x32_bf16(qf[g][d], bk, S[g][j], 0, 0, 0);
            }
        }
        // P = exp(s*scale); causal mask -> 0
        const int kvb = kt * 64 + l16;
        const bool diag = (kt * 64 + 63 > wq0);
#pragma unroll
        for (int g = 0; g < 2; g++) {
            const int qbase = wq0 + g * 16 + quad * 4;
#pragma unroll
            for (int j = 0; j < 4; j++)
#pragma unroll
                for (int r = 0; r < 4; r++) {
                    bool masked = diag && (kvb + j * 16 > qbase + r);
                    float p = masked ? 0.f : __expf(S[g][j][r] * scale);
                    Ps[wave][(g * 16 + quad * 4 + r) * PS_STRIDE + j * 16 + l16] = f2b(p);
                }
        }
        // per-wave LDS RAW fence before cross-lane reads of Ps[wave]
        __asm__ volatile("s_waitcnt lgkmcnt(0)" ::: "memory");
        // O += P(32x64) @ V(64x128); l += P @ ones  (V fragments reused by both g)
#pragma unroll
        for (int ks = 0; ks < 2; ks++) {
            short8 ap[2];
#pragma unroll
            for (int g = 0; g < 2; g++)
                ap[g] = *(const short8*)(Ps[wave] + (g * 16 + l16) * PS_STRIDE + ks * 32 + quad * 8);
#pragma unroll
            for (int dt = 0; dt < 8; dt++) {
                short8 bv = *(const short8*)(Vs + (dt * 16 + l16) * VS_STRIDE + ks * 32 + quad * 8);
#pragma unroll
                for (int g = 0; g < 2; g++)
                    Oacc[g][dt] = __builtin_amdgcn_mfma_f32_16x16x32_bf16(ap[g], bv, Oacc[g][dt], 0, 0, 0);
            }
#pragma unroll
            for (int g = 0; g < 2; g++)
                Ol[g] = __builtin_amdgcn_mfma_f32_16x16x32_bf16(ap[g], ONES, Ol[g], 0, 0, 0);
        }
    }
    // epilogue: y bf16 [b*T + q][h*128 + d]; normalize by l = Ol[g]
#pragma unroll
    for (int g = 0; g < 2; g++)
#pragma unroll
        for (int dt = 0; dt < 8; dt++)
#pragma unroll
            for (int r = 0; r < 4; r++) {
                float v = Oacc[g][dt][r] / Ol[g][r];
                y[(size_t)(b * TT + wq0 + g * 16 + quad * 4 + r) * D_MODEL
                  + h * 128 + dt * 16 + l16] = f2b(v);
            }
}

// ---------------------------------------------------------------------------
// Memory plan (ws use = 25,165,824 B, proven available; inputs/out fp32):
//   ws[0, 16.78M):      xb (phases 1-4) -> Y (attn -> gemm2)
//   ws[16.78M, 25.17M): WqkvT rows 0..2047 (gemm1) -> WoT (gemm2)
//   d_out[0, 25.17M):   QKV bf16 (gemm1 -> attn) -> final fp32 out (gemm2)
//   d_out[25.17M, 33.55M): WqkvT rows 2048..3071 (gemm1 only; dead after)
extern "C" void kernel_launch(void* const* d_in, const int* in_sizes, int n_in,
                              void* d_out, int out_size, void* d_ws, size_t ws_size,
                              hipStream_t stream) {
    const float* x    = (const float*)d_in[0];   // 4096 x 2048 fp32
    const float* Wqkv = (const float*)d_in[1];   // 2048 x 3072 fp32
    const float* Wo   = (const float*)d_in[2];   // 2048 x 2048 fp32
    const int*   sp   = (const int*)d_in[3];

    char* ws = (char*)d_ws;
    char* dob = (char*)d_out;
    u16*   xb     = (u16*)ws;                    // 4096x2048 bf16
    u16*   Y      = (u16*)ws;                    //    (after gemm1: attn output)
    u16*   WqkvTA = (u16*)(ws + 16777216);       // N-rows 0..2047 of Wqkv^T
    u16*   WoT    = (u16*)(ws + 16777216);       //    (after gemm1)
    u16*   QKV    = (u16*)d_out;                 // 4096x3072 bf16
    u16*   WqkvTB = (u16*)(dob + 25165824);      // N-rows 2048..3071 of Wqkv^T
    float* out    = (float*)d_out;

    // 1. x -> bf16
    convert_f2b<<<ROWS * D_MODEL / 4 / 256, 256, 0, stream>>>(x, xb);
    // 2. Wqkv^T split across the two scratch tails
    transpose_f2b<<<dim3(64, 64), 256, 0, stream>>>(Wqkv, WqkvTA, D_MODEL, QKV_DIM, 0);
    transpose_f2b<<<dim3(32, 64), 256, 0, stream>>>(Wqkv, WqkvTB, D_MODEL, QKV_DIM, 2048);
    // 3. QKV = x @ Wqkv with fused RoPE (async m97 structure, fast trig)
    gemm_bt_async<false, true><<<dim3(QKV_DIM / 128, ROWS / 128), 256, 0, stream>>>(
        xb, WqkvTA, WqkvTB, 2048, QKV, ROWS, QKV_DIM, D_MODEL, sp);
    // 4. Wo^T (overwrites WqkvTA, dead)
    transpose_f2b<<<dim3(64, 64), 256, 0, stream>>>(Wo, WoT, D_MODEL, D_MODEL, 0);
    // 5. flash attention -> Y (overwrites xb, dead)
    attn_kernel<<<512, 256, 0, stream>>>(QKV, Y);
    // 6. out = Y @ Wo -> fp32 (overwrites QKV + WqkvTB, dead)
    gemm_bt_async<true, false><<<dim3(D_MODEL / 128, ROWS / 128), 256, 0, stream>>>(
        Y, WoT, WoT, D_MODEL, out, ROWS, D_MODEL, D_MODEL, sp);
}

// Round 3
// 353.793 us; speedup vs baseline: 1.0004x; 1.0004x over previous
//
#include <hip/hip_runtime.h>
#include <math.h>

// Problem constants
#define D_MODEL 2048
#define N_HEADS 16
#define N_KV    4
#define DH      128
#define QKV_DIM 3072   // 2048 + 2*4*128
#define TT      2048   // T
#define BB      2      // B
#define ROWS    (BB*TT)  // 4096

// LDS strides (u16 units)
#define VS_STRIDE 72    // 128 rows (d) x 64 kv (padded)
#define PS_STRIDE 72    // 32 rows (q) x 64 kv (padded)

typedef unsigned short u16;
typedef short short8 __attribute__((ext_vector_type(8)));
typedef short short4v __attribute__((ext_vector_type(4)));
typedef float float4v __attribute__((ext_vector_type(4)));

__device__ inline float b2f(u16 h) {
    union { unsigned u; float f; } v; v.u = ((unsigned)h) << 16; return v.f;
}
__device__ inline u16 f2b(float f) {
    union { float f; unsigned u; } v; v.f = f;
    unsigned r = v.u + 0x7FFF + ((v.u >> 16) & 1);
    return (u16)(r >> 16);
}

// async global->LDS DMA, 16 bytes/lane. LDS dest = wave-uniform base + lane*16.
__device__ inline void async16(const void* g, void* l) {
    __builtin_amdgcn_global_load_lds(
        (const __attribute__((address_space(1))) void*)g,
        (__attribute__((address_space(3))) void*)l, 16, 0, 0);
}

// ---------------------------------------------------------------------------
// fp32 -> bf16 bulk convert (vectorized)
__global__ void convert_f2b(const float* __restrict__ src, u16* __restrict__ dst) {
    int i = blockIdx.x * 256 + threadIdx.x;
    float4v a = *(const float4v*)(src + (size_t)i * 4);
    short4v p;
    p[0] = (short)f2b(a[0]); p[1] = (short)f2b(a[1]);
    p[2] = (short)f2b(a[2]); p[3] = (short)f2b(a[3]);
    *(short4v*)(dst + (size_t)i * 4) = p;
}

// ---------------------------------------------------------------------------
// 32x32 transpose + fp32->bf16: dst[c][r] = bf16(src[r][c + col0]). 256 thr.
__global__ void transpose_f2b(const float* __restrict__ src, u16* __restrict__ dst,
                              int R, int C, int col0) {
    __shared__ __align__(16) u16 tile[32][33];
    int bc = blockIdx.x * 32, br = blockIdx.y * 32;
    int tx = threadIdx.x & 31, ty = threadIdx.x >> 5;   // ty 0..7
    for (int i = ty; i < 32; i += 8)
        tile[i][tx] = f2b(src[(size_t)(br + i) * C + col0 + bc + tx]);
    __syncthreads();
    for (int i = ty; i < 32; i += 8)
        dst[(size_t)(bc + i) * R + br + tx] = tile[tx][i];
}

// ---------------------------------------------------------------------------
// m97-style async GEMM: C[M,N] = A[M,K] @ Bt[N,K]^T, bf16 in, fp32 accum.
// B^T split across two buffers at N-row `nsplit` (workspace tetris).
// ROPE: fused rotary on cols < 2560 (fast hw trig: __sinf/__cosf/__expf).
template<bool F32OUT, bool ROPE>
__global__ __launch_bounds__(256) void gemm_bt_async(
    const u16* __restrict__ A, const u16* __restrict__ Bt1, const u16* __restrict__ Bt2,
    int nsplit, void* __restrict__ Cv, int M, int N, int K, const int* __restrict__ sp) {
    __shared__ __align__(16) u16 As[128 * 32];
    __shared__ __align__(16) u16 Bs[128 * 32];
    const int tid = threadIdx.x;
    const int wave = tid >> 6, lane = tid & 63;
    const int quad = lane >> 4, l16 = lane & 15;
    const int bm = blockIdx.y * 128, bn = blockIdx.x * 128;
    const int wm = (wave >> 1) * 64, wn = (wave & 1) * 64;
    const int srow = wave * 32 + (lane >> 2);
    const int scol = (lane & 3) * 8;
    const u16* Bt = (bn < nsplit) ? (Bt1 + (size_t)bn * K)
                                  : (Bt2 + (size_t)(bn - nsplit) * K);

    float4v acc[4][4] = {};

    for (int k0 = 0; k0 < K; k0 += 32) {
        async16(A + (size_t)(bm + srow) * K + k0 + scol, (char*)As + wave * 2048);
        async16(A + (size_t)(bm + srow + 16) * K + k0 + scol, (char*)As + wave * 2048 + 1024);
        async16(Bt + (size_t)srow * K + k0 + scol, (char*)Bs + wave * 2048);
        async16(Bt + (size_t)(srow + 16) * K + k0 + scol, (char*)Bs + wave * 2048 + 1024);
        __syncthreads();
        short8 af[4], bf[4];
#pragma unroll
        for (int i = 0; i < 4; i++)
            af[i] = *(const short8*)(As + (wm + i * 16 + l16) * 32 + quad * 8);
#pragma unroll
        for (int j = 0; j < 4; j++)
            bf[j] = *(const short8*)(Bs + (wn + j * 16 + l16) * 32 + quad * 8);
#pragma unroll
        for (int i = 0; i < 4; i++)
#pragma unroll
            for (int j = 0; j < 4; j++)
                acc[i][j] = __builtin_amdgcn_mfma_f32_16x16x32_bf16(af[i], bf[j], acc[i][j], 0, 0, 0);
        __syncthreads();
    }
    const int sp0 = ROPE ? *sp : 0;
    // epilogue: C/D layout col=lane&15, row=quad*4+reg (m89/m91-verified).
#pragma unroll
    for (int j = 0; j < 4; j++) {
        int col = bn + wn + j * 16 + l16;
        bool do_rope = ROPE && (col < 2560);
        float inv = 0.f;
        if (do_rope) inv = __expf(-0.14391156816f * (float)((col & 127) >> 1));
#pragma unroll
        for (int i = 0; i < 4; i++) {
            int row0 = bm + wm + i * 16 + quad * 4;
#pragma unroll
            for (int r = 0; r < 4; r++) {
                float v = acc[i][j][r];
                if (do_rope) {
                    float partner = __shfl_xor(v, 1, 64);
                    float ang = (float)(sp0 + ((row0 + r) & (TT - 1))) * inv;
                    float c = __cosf(ang), s = __sinf(ang);
                    v = (col & 1) ? (partner * s + v * c)
                                  : (v * c - partner * s);
                }
                if (F32OUT) ((float*)Cv)[(size_t)(row0 + r) * N + col] = v;
                else        ((u16*)Cv)[(size_t)(row0 + r) * N + col] = f2b(v);
            }
        }
    }
}

// ---------------------------------------------------------------------------
// Flash attention v8: 256 threads = 4 waves, q-tile 128 rows (32/wave).
// vs v7: q-slot map re-encoded for ADJACENT-pair CU assignment. Evidence
// (rounds 0/1): all 512 blocks co-resident (2/CU), identical 103.4us under
// two maps whose only common worst case is same-qq adjacent pairs jj=2c,2c+1
// -> CU pairing is consecutive stream items within an XCD, NOT (jj, jj+32).
// New map: h=(jj>>1)&3, s=jj>>3, qt = (jj&1) ? 15-s : s. Pair (2c,2c+1)
// shares (h,s), differs in parity -> qt sum = 15 -> every CU does exactly
// 34 kv-tiles (was 12..64).
// K staged via global_load_lds double-buffer with XOR-SWIZZLED layout:
//   LDS[row][c] = global[row][c ^ (row&7)]  (c = 8-u16 chunk index)
// XCD swizzle bx&7 -> (b,hk). Fixed-offset softmax; l via ones MFMA.
__global__ __launch_bounds__(256, 2) void attn_kernel(
    const u16* __restrict__ qkv, u16* __restrict__ y) {
    __shared__ __align__(16) u16 Ks[2][64 * 128];          // 2 x 16384 B
    __shared__ __align__(16) u16 Vs[128 * VS_STRIDE];      // 18432 B
    __shared__ __align__(16) u16 Ps[4][32 * PS_STRIDE];    // 18432 B (total 69632)

    const int tid = threadIdx.x;
    const int wave = tid >> 6, lane = tid & 63;
    const int quad = lane >> 4, l16 = lane & 15;
    const int bx = blockIdx.x;
    const int xg = bx & 7;             // XCD group = (b, hk)
    const int b = xg >> 2, hk = xg & 3;
    const int jj = bx >> 3;            // 0..63 within group = XCD stream pos
    // adjacent-pair balance: CU gets stream items (2c, 2c+1) -> same (h,s),
    // opposite parity -> qt + qt' = 15 -> uniform 34 kv-tiles per CU.
    const int h = hk * 4 + ((jj >> 1) & 3);
    const int s = jj >> 3;             // 0..7
    const int qt = (jj & 1) ? (15 - s) : s;
    const int qcol = h * 128;
    const int kcol = 2048 + hk * 128;
    const int vcol = 2560 + hk * 128;
    const float scale = 0.08838834764831845f;  // 1/sqrt(128)

    // Q fragments in registers (reused every kv-tile): 2 row-groups of 16
    const int wq0 = qt * 128 + wave * 32;
    short8 qf[2][4];
#pragma unroll
    for (int g = 0; g < 2; g++) {
        const u16* qrow = qkv + (size_t)(b * TT + wq0 + g * 16 + l16) * QKV_DIM + qcol;
#pragma unroll
        for (int d = 0; d < 4; d++)
            qf[g][d] = *(const short8*)(qrow + d * 32 + quad * 8);
    }

    // Oacc[g][0..7]: O tiles (2 x 16 x 128). Ol[g]: row-sum l via ones-column.
    float4v Oacc[2][8] = {};
    float4v Ol[2] = {};
    const short8 ONES = {(short)0x3F80, (short)0x3F80, (short)0x3F80, (short)0x3F80,
                         (short)0x3F80, (short)0x3F80, (short)0x3F80, (short)0x3F80};

    const int ktmax = 2 * qt + 1;

    // K DMA source offsets with XOR swizzle. Instruction si of wave covers LDS
    // rows wave*16 + si*4 + quad, chunk l16; source chunk = l16 ^ (row&7).
    size_t kg[4];
#pragma unroll
    for (int si = 0; si < 4; si++) {
        int rl = (si * 4 + quad) & 7;          // row&7 (wave*16 is 0 mod 8)
        kg[si] = (size_t)(wave * 16 + si * 4 + quad) * QKV_DIM
               + (size_t)((l16 ^ rl) * 8);
    }
    // kt=0 prefetch: K via DMA, V via registers
    {
        const u16* kb = qkv + (size_t)(b * TT) * QKV_DIM;
#pragma unroll
        for (int si = 0; si < 4; si++)
            async16(kb + kcol + kg[si], (char*)Ks[0] + wave * 4096 + si * 1024);
    }
    short8 vreg[4];
#pragma unroll
    for (int si = 0; si < 4; si++)
        vreg[si] = *(const short8*)(qkv + (size_t)(b * TT + lane) * QKV_DIM + vcol + (wave * 4 + si) * 8);

    for (int kt = 0; kt <= ktmax; kt++) {
        const u16* Kcur = Ks[kt & 1];
        __syncthreads();   // drains K-DMA + V prefetch; prev tile's readers done
        // commit V (transposed) to LDS: consecutive-u16 stores, conflict-free
#pragma unroll
        for (int si = 0; si < 4; si++) {
            int dgi = wave * 4 + si;
#pragma unroll
            for (int j8 = 0; j8 < 8; j8++)
                Vs[(dgi * 8 + j8) * VS_STRIDE + lane] = (u16)vreg[si][j8];
        }
        __syncthreads();   // Vs visible
        if (kt < ktmax) {  // prefetch next tile (overlaps all compute below)
            const u16* kb = qkv + (size_t)(b * TT + (kt + 1) * 64) * QKV_DIM;
#pragma unroll
            for (int si = 0; si < 4; si++)
                async16(kb + kcol + kg[si], (char*)Ks[(kt + 1) & 1] + wave * 4096 + si * 1024);
#pragma unroll
            for (int si = 0; si < 4; si++)
                vreg[si] = *(const short8*)(kb + (size_t)lane * QKV_DIM + vcol + (wave * 4 + si) * 8);
        }

        // S = Q*K^T  (K read through XOR swizzle; each K fragment feeds BOTH
        // q row-groups -> K LDS read traffic amortized over 32 q-rows)
        float4v S[2][4] = {};
#pragma unroll
        for (int d = 0; d < 4; d++) {
#pragma unroll
            for (int j = 0; j < 4; j++) {
                short8 bk = *(const short8*)(Kcur + (j * 16 + l16) * 128
                                             + (((d * 4 + quad) ^ (l16 & 7)) * 8));
#pragma unroll
                for (int g = 0; g < 2; g++)
                    S[g][j] = __builtin_amdgcn_mfma_f32_16x16x32_bf16(qf[g][d], bk, S[g][j], 0, 0, 0);
            }
        }
        // P = exp(s*scale); causal mask -> 0
        const int kvb = kt * 64 + l16;
        const bool diag = (kt * 64 + 63 > wq0);
#pragma unroll
        for (int g = 0; g < 2; g++) {
            const int qbase = wq0 + g * 16 + quad * 4;
#pragma unroll
            for (int j = 0; j < 4; j++)
#pragma unroll
                for (int r = 0; r < 4; r++) {
                    bool masked = diag && (kvb + j * 16 > qbase + r);
                    float p = masked ? 0.f : __expf(S[g][j][r] * scale);
                    Ps[wave][(g * 16 + quad * 4 + r) * PS_STRIDE + j * 16 + l16] = f2b(p);
                }
        }
        // per-wave LDS RAW fence before cross-lane reads of Ps[wave]
        __asm__ volatile("s_waitcnt lgkmcnt(0)" ::: "memory");
        // O += P(32x64) @ V(64x128); l += P @ ones  (V fragments reused by both g)
#pragma unroll
        for (int ks = 0; ks < 2; ks++) {
            short8 ap[2];
#pragma unroll
            for (int g = 0; g < 2; g++)
                ap[g] = *(const short8*)(Ps[wave] + (g * 16 + l16) * PS_STRIDE + ks * 32 + quad * 8);
#pragma unroll
            for (int dt = 0; dt < 8; dt++) {
                short8 bv = *(const short8*)(Vs + (dt * 16 + l16) * VS_STRIDE + ks * 32 + quad * 8);
#pragma unroll
                for (int g = 0; g < 2; g++)
                    Oacc[g][dt] = __builtin_amdgcn_mfma_f32_16x16x32_bf16(ap[g], bv, Oacc[g][dt], 0, 0, 0);
            }
#pragma unroll
            for (int g = 0; g < 2; g++)
                Ol[g] = __builtin_amdgcn_mfma_f32_16x16x32_bf16(ap[g], ONES, Ol[g], 0, 0, 0);
        }
    }
    // epilogue: y bf16 [b*T + q][h*128 + d]; normalize by l = Ol[g]
#pragma unroll
    for (int g = 0; g < 2; g++)
#pragma unroll
        for (int dt = 0; dt < 8; dt++)
#pragma unroll
            for (int r = 0; r < 4; r++) {
                float v = Oacc[g][dt][r] / Ol[g][r];
                y[(size_t)(b * TT + wq0 + g * 16 + quad * 4 + r) * D_MODEL
                  + h * 128 + dt * 16 + l16] = f2b(v);
            }
}

// ---------------------------------------------------------------------------
// Memory plan (ws use = 25,165,824 B, proven available; inputs/out fp32):
//   ws[0, 16.78M):      xb (phases 1-4) -> Y (attn -> gemm2)
//   ws[16.78M, 25.17M): WqkvT rows 0..2047 (gemm1) -> WoT (gemm2)
//   d_out[0, 25.17M):   QKV bf16 (gemm1 -> attn) -> final fp32 out (gemm2)
//   d_out[25.17M, 33.55M): WqkvT rows 2048..3071 (gemm1 only; dead after)
extern "C" void kernel_launch(void* const* d_in, const int* in_sizes, int n_in,
                              void* d_out, int out_size, void* d_ws, size_t ws_size,
                              hipStream_t stream) {
    const float* x    = (const float*)d_in[0];   // 4096 x 2048 fp32
    const float* Wqkv = (const float*)d_in[1];   // 2048 x 3072 fp32
    const float* Wo   = (const float*)d_in[2];   // 2048 x 2048 fp32
    const int*   sp   = (const int*)d_in[3];

    char* ws = (char*)d_ws;
    char* dob = (char*)d_out;
    u16*   xb     = (u16*)ws;                    // 4096x2048 bf16
    u16*   Y      = (u16*)ws;                    //    (after gemm1: attn output)
    u16*   WqkvTA = (u16*)(ws + 16777216);       // N-rows 0..2047 of Wqkv^T
    u16*   WoT    = (u16*)(ws + 16777216);       //    (after gemm1)
    u16*   QKV    = (u16*)d_out;                 // 4096x3072 bf16
    u16*   WqkvTB = (u16*)(dob + 25165824);      // N-rows 2048..3071 of Wqkv^T
    float* out    = (float*)d_out;

    // 1. x -> bf16
    convert_f2b<<<ROWS * D_MODEL / 4 / 256, 256, 0, stream>>>(x, xb);
    // 2. Wqkv^T split across the two scratch tails
    transpose_f2b<<<dim3(64, 64), 256, 0, stream>>>(Wqkv, WqkvTA, D_MODEL, QKV_DIM, 0);
    transpose_f2b<<<dim3(32, 64), 256, 0, stream>>>(Wqkv, WqkvTB, D_MODEL, QKV_DIM, 2048);
    // 3. QKV = x @ Wqkv with fused RoPE (async m97 structure, fast trig)
    gemm_bt_async<false, true><<<dim3(QKV_DIM / 128, ROWS / 128), 256, 0, stream>>>(
        xb, WqkvTA, WqkvTB, 2048, QKV, ROWS, QKV_DIM, D_MODEL, sp);
    // 4. Wo^T (overwrites WqkvTA, dead)
    transpose_f2b<<<dim3(64, 64), 256, 0, stream>>>(Wo, WoT, D_MODEL, D_MODEL, 0);
    // 5. flash attention -> Y (overwrites xb, dead)
    attn_kernel<<<512, 256, 0, stream>>>(QKV, Y);
    // 6. out = Y @ Wo -> fp32 (overwrites QKV + WqkvTB, dead)
    gemm_bt_async<true, false><<<dim3(D_MODEL / 128, ROWS / 128), 256, 0, stream>>>(
        Y, WoT, WoT, D_MODEL, out, ROWS, D_MODEL, D_MODEL, sp);
}

// Round 4
// 350.917 us; speedup vs baseline: 1.0086x; 1.0082x over previous
//
#include <hip/hip_runtime.h>
#include <math.h>

// Problem constants
#define D_MODEL 2048
#define N_HEADS 16
#define N_KV    4
#define DH      128
#define QKV_DIM 3072   // 2048 + 2*4*128
#define TT      2048   // T
#define BB      2      // B
#define ROWS    (BB*TT)  // 4096

// Packed QKV layout in d_out (u16 offsets). Written by gemm1 epilogue:
//   Qp[b][h][t][d]   : ((b*16+h)*2048 + t)*128 + d          @ 0
//   Kp[g][t][d]      : (g*2048 + t)*128 + d                 @ 8,388,608   (g=b*4+hk)
//   Vt[g][d][t]      : (g*128 + d)*2048 + t                 @ 10,485,760  (V pre-transposed)
// Total 12,582,912 u16 = 25,165,824 B (same region/lifetime as old QKV).
#define QP_OFF 0u
#define KP_OFF 8388608u
#define VT_OFF 10485760u

typedef unsigned short u16;
typedef short short8 __attribute__((ext_vector_type(8)));
typedef short short4v __attribute__((ext_vector_type(4)));
typedef float float4v __attribute__((ext_vector_type(4)));

__device__ inline u16 f2b(float f) {
    union { float f; unsigned u; } v; v.f = f;
    unsigned r = v.u + 0x7FFF + ((v.u >> 16) & 1);
    return (u16)(r >> 16);
}

// async global->LDS DMA, 16 bytes/lane. LDS dest = wave-uniform base + lane*16.
__device__ inline void async16(const void* g, void* l) {
    __builtin_amdgcn_global_load_lds(
        (const __attribute__((address_space(1))) void*)g,
        (__attribute__((address_space(3))) void*)l, 16, 0, 0);
}

// ---------------------------------------------------------------------------
// fp32 -> bf16 bulk convert (vectorized)
__global__ void convert_f2b(const float* __restrict__ src, u16* __restrict__ dst) {
    int i = blockIdx.x * 256 + threadIdx.x;
    float4v a = *(const float4v*)(src + (size_t)i * 4);
    short4v p;
    p[0] = (short)f2b(a[0]); p[1] = (short)f2b(a[1]);
    p[2] = (short)f2b(a[2]); p[3] = (short)f2b(a[3]);
    *(short4v*)(dst + (size_t)i * 4) = p;
}

// ---------------------------------------------------------------------------
// 32x32 transpose + fp32->bf16: dst[c][r] = bf16(src[r][c + col0]). 256 thr.
__global__ void transpose_f2b(const float* __restrict__ src, u16* __restrict__ dst,
                              int R, int C, int col0) {
    __shared__ __align__(16) u16 tile[32][33];
    int bc = blockIdx.x * 32, br = blockIdx.y * 32;
    int tx = threadIdx.x & 31, ty = threadIdx.x >> 5;   // ty 0..7
    for (int i = ty; i < 32; i += 8)
        tile[i][tx] = f2b(src[(size_t)(br + i) * C + col0 + bc + tx]);
    __syncthreads();
    for (int i = ty; i < 32; i += 8)
        dst[(size_t)(bc + i) * R + br + tx] = tile[tx][i];
}

// ---------------------------------------------------------------------------
// m97-style async GEMM: C[M,N] = A[M,K] @ Bt[N,K]^T, bf16 in, fp32 accum.
// B^T split across two buffers at N-row `nsplit` (workspace tetris).
// ROPE: fused rotary on cols < 2560 (fast hw trig: __sinf/__cosf/__expf).
// !F32OUT (gemm1): writes the PACKED QKV layout (Qp/Kp/Vt) — per-element
// stores anyway, so the remap is free; V is written pre-transposed so attn
// can DMA V^T tiles linearly instead of a 64-line scatter-gather.
template<bool F32OUT, bool ROPE>
__global__ __launch_bounds__(256) void gemm_bt_async(
    const u16* __restrict__ A, const u16* __restrict__ Bt1, const u16* __restrict__ Bt2,
    int nsplit, void* __restrict__ Cv, int M, int N, int K, const int* __restrict__ sp) {
    __shared__ __align__(16) u16 As[128 * 32];
    __shared__ __align__(16) u16 Bs[128 * 32];
    const int tid = threadIdx.x;
    const int wave = tid >> 6, lane = tid & 63;
    const int quad = lane >> 4, l16 = lane & 15;
    const int bm = blockIdx.y * 128, bn = blockIdx.x * 128;
    const int wm = (wave >> 1) * 64, wn = (wave & 1) * 64;
    const int srow = wave * 32 + (lane >> 2);
    const int scol = (lane & 3) * 8;
    const u16* Bt = (bn < nsplit) ? (Bt1 + (size_t)bn * K)
                                  : (Bt2 + (size_t)(bn - nsplit) * K);

    float4v acc[4][4] = {};

    for (int k0 = 0; k0 < K; k0 += 32) {
        async16(A + (size_t)(bm + srow) * K + k0 + scol, (char*)As + wave * 2048);
        async16(A + (size_t)(bm + srow + 16) * K + k0 + scol, (char*)As + wave * 2048 + 1024);
        async16(Bt + (size_t)srow * K + k0 + scol, (char*)Bs + wave * 2048);
        async16(Bt + (size_t)(srow + 16) * K + k0 + scol, (char*)Bs + wave * 2048 + 1024);
        __syncthreads();
        short8 af[4], bf[4];
#pragma unroll
        for (int i = 0; i < 4; i++)
            af[i] = *(const short8*)(As + (wm + i * 16 + l16) * 32 + quad * 8);
#pragma unroll
        for (int j = 0; j < 4; j++)
            bf[j] = *(const short8*)(Bs + (wn + j * 16 + l16) * 32 + quad * 8);
#pragma unroll
        for (int i = 0; i < 4; i++)
#pragma unroll
            for (int j = 0; j < 4; j++)
                acc[i][j] = __builtin_amdgcn_mfma_f32_16x16x32_bf16(af[i], bf[j], acc[i][j], 0, 0, 0);
        __syncthreads();
    }
    const int sp0 = ROPE ? *sp : 0;
    // epilogue: C/D layout col=lane&15, row=quad*4+reg (m89/m91-verified).
#pragma unroll
    for (int j = 0; j < 4; j++) {
        int col = bn + wn + j * 16 + l16;
        bool do_rope = ROPE && (col < 2560);
        float inv = 0.f;
        if (do_rope) inv = __expf(-0.14391156816f * (float)((col & 127) >> 1));
#pragma unroll
        for (int i = 0; i < 4; i++) {
            int row0 = bm + wm + i * 16 + quad * 4;
#pragma unroll
            for (int r = 0; r < 4; r++) {
                float v = acc[i][j][r];
                if (do_rope) {
                    float partner = __shfl_xor(v, 1, 64);
                    float ang = (float)(sp0 + ((row0 + r) & (TT - 1))) * inv;
                    float c = __cosf(ang), s = __sinf(ang);
                    v = (col & 1) ? (partner * s + v * c)
                                  : (v * c - partner * s);
                }
                if (F32OUT) {
                    ((float*)Cv)[(size_t)(row0 + r) * N + col] = v;
                } else {
                    // packed QKV store (region is wave-uniform per j-block)
                    int rw = row0 + r;
                    int bb = rw >> 11, t = rw & 2047;
                    size_t addr;
                    if (col < 2048)
                        addr = QP_OFF + (size_t)(bb * 16 + (col >> 7)) * 262144
                             + (size_t)t * 128 + (col & 127);
                    else if (col < 2560)
                        addr = KP_OFF + (size_t)(bb * 4 + ((col - 2048) >> 7)) * 262144
                             + (size_t)t * 128 + (col & 127);
                    else
                        addr = VT_OFF + (size_t)(bb * 4 + ((col - 2560) >> 7)) * 262144
                             + (size_t)(col & 127) * 2048 + t;
                    ((u16*)Cv)[addr] = f2b(v);
                }
            }
        }
    }
}

// ---------------------------------------------------------------------------
// Flash attention v9: 256 threads = 4 waves, q-tile 128 rows (32/wave).
// vs v8 (structural, from packed-QKV layout):
//  - V^T staged via global_load_lds DMA (like K): the 64-scattered-line
//    register gather + 32 ds_write transpose-commit + ONE BARRIER per
//    iteration are eliminated. Single __syncthreads per kv-tile.
//  - Ps pad replaced by XOR swizzle -> LDS = 2x16K(K) + 2x16K(V^T) + 16K(P)
//    = 81,920 B = exactly 2 blocks/CU.
// Swizzles (all involutions, write-side == read-side, rule #21):
//   K : LDS[row][c]  = K [row][c ^ (row&7)]   (c = 8-u16 chunk, 16/row)
//   V^T: LDS[d][c]   = Vt[d][c ^ (d&7)]       (c = 8-u16 chunk, 8/row)
//   P : LDS[rq][c]   = P [rq][c ^ (rq&7)]     (c = 8-u16 chunk, 8/row)
// Fixed-offset softmax; l via ones MFMA. XCD swizzle bx&7 -> (b,hk).
__global__ __launch_bounds__(256, 2) void attn_kernel(
    const u16* __restrict__ qkv, u16* __restrict__ y) {
    __shared__ __align__(16) u16 Ks[2][64 * 128];   // 2 x 16384 B
    __shared__ __align__(16) u16 Vs[2][128 * 64];   // 2 x 16384 B (V^T: d rows)
    __shared__ __align__(16) u16 Ps[4][32 * 64];    // 16384 B  (total 81920)

    const int tid = threadIdx.x;
    const int wave = tid >> 6, lane = tid & 63;
    const int quad = lane >> 4, l16 = lane & 15;
    const int bx = blockIdx.x;
    const int xg = bx & 7;             // XCD group = (b, hk)
    const int b = xg >> 2, hk = xg & 3;
    const int jj = bx >> 3;            // 0..63 within group
    const int h = hk * 4 + ((jj >> 1) & 3);
    const int s = jj >> 3;             // 0..7
    const int qt = (jj & 1) ? (15 - s) : s;
    const int g = b * 4 + hk;
    const float scale = 0.08838834764831845f;  // 1/sqrt(128)

    // Q fragments in registers (reused every kv-tile): 2 row-groups of 16
    const int wq0 = qt * 128 + wave * 32;
    const u16* qbase = qkv + QP_OFF + (size_t)(b * 16 + h) * 262144;
    short8 qf[2][4];
#pragma unroll
    for (int gi = 0; gi < 2; gi++) {
        const u16* qrow = qbase + (size_t)(wq0 + gi * 16 + l16) * 128;
#pragma unroll
        for (int d = 0; d < 4; d++)
            qf[gi][d] = *(const short8*)(qrow + d * 32 + quad * 8);
    }

    // Oacc[gi][0..7]: O tiles (2 x 16 x 128). Ol[gi]: row-sum l via ones MFMA.
    float4v Oacc[2][8] = {};
    float4v Ol[2] = {};
    const short8 ONES = {(short)0x3F80, (short)0x3F80, (short)0x3F80, (short)0x3F80,
                         (short)0x3F80, (short)0x3F80, (short)0x3F80, (short)0x3F80};

    const int ktmax = 2 * qt + 1;

    // K DMA source offsets (tile-relative; row stride 128 u16, 16 chunks/row).
    // Instr si covers LDS rows wave*16+si*4+quad, chunk l16; src chunk ^row&7.
    size_t kg[4];
#pragma unroll
    for (int si = 0; si < 4; si++) {
        int kr = wave * 16 + si * 4 + quad;
        kg[si] = (size_t)kr * 128 + (size_t)((l16 ^ (kr & 7)) * 8);
    }
    // V^T DMA source offsets (tile-relative; Vt row stride 2048 u16 = full T;
    // LDS rows = d, 8 chunks/row). Instr si covers LDS rows wave*32+si*8+
    // (lane>>3), chunk lane&7; src chunk ^ d&7.  (d&7 == lane>>3 here.)
    size_t vg[4];
#pragma unroll
    for (int si = 0; si < 4; si++) {
        int vr = wave * 32 + si * 8 + (lane >> 3);
        vg[si] = (size_t)vr * 2048 + (size_t)(((lane & 7) ^ (lane >> 3)) * 8);
    }
    const u16* Kb = qkv + KP_OFF + (size_t)g * 262144;
    const u16* Vb = qkv + VT_OFF + (size_t)g * 262144;

    // kt=0 prefetch (both K and V^T via DMA)
#pragma unroll
    for (int si = 0; si < 4; si++)
        async16(Kb + kg[si], (char*)Ks[0] + wave * 4096 + si * 1024);
#pragma unroll
    for (int si = 0; si < 4; si++)
        async16(Vb + vg[si], (char*)Vs[0] + wave * 4096 + si * 1024);

    for (int kt = 0; kt <= ktmax; kt++) {
        const int cur = kt & 1;
        __syncthreads();   // vmcnt(0)+barrier: DMA for buf[cur] complete; all
                           // waves done reading buf[cur^1] from prev iter.
        if (kt < ktmax) {  // prefetch next tile into buf[cur^1]
#pragma unroll
            for (int si = 0; si < 4; si++)
                async16(Kb + (size_t)(kt + 1) * 8192 + kg[si],
                        (char*)Ks[cur ^ 1] + wave * 4096 + si * 1024);
#pragma unroll
            for (int si = 0; si < 4; si++)
                async16(Vb + (size_t)(kt + 1) * 64 + vg[si],
                        (char*)Vs[cur ^ 1] + wave * 4096 + si * 1024);
        }
        const u16* Kcur = Ks[cur];
        const u16* Vcur = Vs[cur];

        // S = Q*K^T  (K read through XOR swizzle; each K fragment feeds BOTH
        // q row-groups)
        float4v S[2][4] = {};
#pragma unroll
        for (int d = 0; d < 4; d++) {
#pragma unroll
            for (int j = 0; j < 4; j++) {
                short8 bk = *(const short8*)(Kcur + (j * 16 + l16) * 128
                                             + (((d * 4 + quad) ^ (l16 & 7)) * 8));
#pragma unroll
                for (int gi = 0; gi < 2; gi++)
                    S[gi][j] = __builtin_amdgcn_mfma_f32_16x16x32_bf16(qf[gi][d], bk, S[gi][j], 0, 0, 0);
            }
        }
        // P = exp(s*scale); causal mask -> 0.  Ps XOR-swizzled:
        // element (rq, kv=j*16+l16) -> chunk (j*2+(l16>>3))^(rq&7), pos l16&7.
        const int kvb = kt * 64 + l16;
        const bool diag = (kt * 64 + 63 > wq0);
#pragma unroll
        for (int gi = 0; gi < 2; gi++) {
            const int qbq = wq0 + gi * 16 + quad * 4;
#pragma unroll
            for (int j = 0; j < 4; j++)
#pragma unroll
                for (int r = 0; r < 4; r++) {
                    bool masked = diag && (kvb + j * 16 > qbq + r);
                    float p = masked ? 0.f : __expf(S[gi][j][r] * scale);
                    int rq = gi * 16 + quad * 4 + r;
                    int ch = (j * 2 + (l16 >> 3)) ^ (rq & 7);
                    Ps[wave][rq * 64 + ch * 8 + (l16 & 7)] = f2b(p);
                }
        }
        // per-wave LDS RAW fence before cross-lane reads of Ps[wave]
        __asm__ volatile("s_waitcnt lgkmcnt(0)" ::: "memory");
        // O += P(32x64) @ V(64x128); l += P @ ones
#pragma unroll
        for (int ks = 0; ks < 2; ks++) {
            short8 ap[2];
#pragma unroll
            for (int gi = 0; gi < 2; gi++)
                ap[gi] = *(const short8*)(Ps[wave] + (gi * 16 + l16) * 64
                                          + (((ks * 4 + quad) ^ (l16 & 7)) * 8));
#pragma unroll
            for (int dt = 0; dt < 8; dt++) {
                short8 bv = *(const short8*)(Vcur + (dt * 16 + l16) * 64
                                             + (((ks * 4 + quad) ^ (l16 & 7)) * 8));
#pragma unroll
                for (int gi = 0; gi < 2; gi++)
                    Oacc[gi][dt] = __builtin_amdgcn_mfma_f32_16x16x32_bf16(ap[gi], bv, Oacc[gi][dt], 0, 0, 0);
            }
#pragma unroll
            for (int gi = 0; gi < 2; gi++)
                Ol[gi] = __builtin_amdgcn_mfma_f32_16x16x32_bf16(ap[gi], ONES, Ol[gi], 0, 0, 0);
        }
    }
    // epilogue: y bf16 [b*T + q][h*128 + d]; normalize by l = Ol[gi]
#pragma unroll
    for (int gi = 0; gi < 2; gi++)
#pragma unroll
        for (int dt = 0; dt < 8; dt++)
#pragma unroll
            for (int r = 0; r < 4; r++) {
                float v = Oacc[gi][dt][r] / Ol[gi][r];
                y[(size_t)(b * TT + wq0 + gi * 16 + quad * 4 + r) * D_MODEL
                  + h * 128 + dt * 16 + l16] = f2b(v);
            }
}

// ---------------------------------------------------------------------------
// Memory plan (ws use = 25,165,824 B, proven available; inputs/out fp32):
//   ws[0, 16.78M):      xb (phases 1-4) -> Y (attn -> gemm2)
//   ws[16.78M, 25.17M): WqkvT rows 0..2047 (gemm1) -> WoT (gemm2)
//   d_out[0, 25.17M):   packed Qp/Kp/Vt bf16 (gemm1 -> attn) -> final fp32 out
//   d_out[25.17M, 33.55M): WqkvT rows 2048..3071 (gemm1 only; dead after)
extern "C" void kernel_launch(void* const* d_in, const int* in_sizes, int n_in,
                              void* d_out, int out_size, void* d_ws, size_t ws_size,
                              hipStream_t stream) {
    const float* x    = (const float*)d_in[0];   // 4096 x 2048 fp32
    const float* Wqkv = (const float*)d_in[1];   // 2048 x 3072 fp32
    const float* Wo   = (const float*)d_in[2];   // 2048 x 2048 fp32
    const int*   sp   = (const int*)d_in[3];

    char* ws = (char*)d_ws;
    char* dob = (char*)d_out;
    u16*   xb     = (u16*)ws;                    // 4096x2048 bf16
    u16*   Y      = (u16*)ws;                    //    (after gemm1: attn output)
    u16*   WqkvTA = (u16*)(ws + 16777216);       // N-rows 0..2047 of Wqkv^T
    u16*   WoT    = (u16*)(ws + 16777216);       //    (after gemm1)
    u16*   QKVp   = (u16*)d_out;                 // packed Qp/Kp/Vt bf16
    u16*   WqkvTB = (u16*)(dob + 25165824);      // N-rows 2048..3071 of Wqkv^T
    float* out    = (float*)d_out;

    // 1. x -> bf16
    convert_f2b<<<ROWS * D_MODEL / 4 / 256, 256, 0, stream>>>(x, xb);
    // 2. Wqkv^T split across the two scratch tails
    transpose_f2b<<<dim3(64, 64), 256, 0, stream>>>(Wqkv, WqkvTA, D_MODEL, QKV_DIM, 0);
    transpose_f2b<<<dim3(32, 64), 256, 0, stream>>>(Wqkv, WqkvTB, D_MODEL, QKV_DIM, 2048);
    // 3. packed QKV = x @ Wqkv with fused RoPE (async m97 structure, fast trig)
    gemm_bt_async<false, true><<<dim3(QKV_DIM / 128, ROWS / 128), 256, 0, stream>>>(
        xb, WqkvTA, WqkvTB, 2048, QKVp, ROWS, QKV_DIM, D_MODEL, sp);
    // 4. Wo^T (overwrites WqkvTA, dead)
    transpose_f2b<<<dim3(64, 64), 256, 0, stream>>>(Wo, WoT, D_MODEL, D_MODEL, 0);
    // 5. flash attention -> Y (overwrites xb, dead)
    attn_kernel<<<512, 256, 0, stream>>>(QKVp, Y);
    // 6. out = Y @ Wo -> fp32 (overwrites packed QKV + WqkvTB, dead)
    gemm_bt_async<true, false><<<dim3(D_MODEL / 128, ROWS / 128), 256, 0, stream>>>(
        Y, WoT, WoT, D_MODEL, out, ROWS, D_MODEL, D_MODEL, sp);
}

// Round 5
// 343.916 us; speedup vs baseline: 1.0291x; 1.0204x over previous
//
#include <hip/hip_runtime.h>
#include <math.h>

// Problem constants
#define D_MODEL 2048
#define N_HEADS 16
#define N_KV    4
#define DH      128
#define QKV_DIM 3072   // 2048 + 2*4*128
#define TT      2048   // T
#define BB      2      // B
#define ROWS    (BB*TT)  // 4096

// Packed QKV layout in d_out (u16 offsets). Written by gemm1 epilogue:
//   Qp[b][h][t][d]   : ((b*16+h)*2048 + t)*128 + d          @ 0
//   Kp[g][t][d]      : (g*2048 + t)*128 + d                 @ 8,388,608   (g=b*4+hk)
//   Vt[g][d][t]      : (g*128 + d)*2048 + t                 @ 10,485,760  (V pre-transposed)
// Total 12,582,912 u16 = 25,165,824 B (same region/lifetime as old QKV).
#define QP_OFF 0u
#define KP_OFF 8388608u
#define VT_OFF 10485760u

typedef unsigned short u16;
typedef short short8 __attribute__((ext_vector_type(8)));
typedef short short4v __attribute__((ext_vector_type(4)));
typedef float float4v __attribute__((ext_vector_type(4)));

__device__ inline u16 f2b(float f) {
    union { float f; unsigned u; } v; v.f = f;
    unsigned r = v.u + 0x7FFF + ((v.u >> 16) & 1);
    return (u16)(r >> 16);
}

// async global->LDS DMA, 16 bytes/lane. LDS dest = wave-uniform base + lane*16.
__device__ inline void async16(const void* g, void* l) {
    __builtin_amdgcn_global_load_lds(
        (const __attribute__((address_space(1))) void*)g,
        (__attribute__((address_space(3))) void*)l, 16, 0, 0);
}

// ---------------------------------------------------------------------------
// fp32 -> bf16 bulk convert (vectorized)
__global__ void convert_f2b(const float* __restrict__ src, u16* __restrict__ dst) {
    int i = blockIdx.x * 256 + threadIdx.x;
    float4v a = *(const float4v*)(src + (size_t)i * 4);
    short4v p;
    p[0] = (short)f2b(a[0]); p[1] = (short)f2b(a[1]);
    p[2] = (short)f2b(a[2]); p[3] = (short)f2b(a[3]);
    *(short4v*)(dst + (size_t)i * 4) = p;
}

// ---------------------------------------------------------------------------
// 32x32 transpose + fp32->bf16: dst[c][r] = bf16(src[r][c + col0]). 256 thr.
__global__ void transpose_f2b(const float* __restrict__ src, u16* __restrict__ dst,
                              int R, int C, int col0) {
    __shared__ __align__(16) u16 tile[32][33];
    int bc = blockIdx.x * 32, br = blockIdx.y * 32;
    int tx = threadIdx.x & 31, ty = threadIdx.x >> 5;   // ty 0..7
    for (int i = ty; i < 32; i += 8)
        tile[i][tx] = f2b(src[(size_t)(br + i) * C + col0 + bc + tx]);
    __syncthreads();
    for (int i = ty; i < 32; i += 8)
        dst[(size_t)(bc + i) * R + br + tx] = tile[tx][i];
}

// ---------------------------------------------------------------------------
// m97-style async GEMM: C[M,N] = A[M,K] @ Bt[N,K]^T, bf16 in, fp32 accum.
// B^T split across two buffers at N-row `nsplit` (workspace tetris).
// ROPE: fused rotary on cols < 2560 (fast hw trig: __sinf/__cosf/__expf).
// !F32OUT (gemm1): writes the PACKED QKV layout (Qp/Kp/Vt) — per-element
// stores anyway, so the remap is free; V is written pre-transposed so attn
// can DMA V^T tiles linearly instead of a 64-line scatter-gather.
template<bool F32OUT, bool ROPE>
__global__ __launch_bounds__(256) void gemm_bt_async(
    const u16* __restrict__ A, const u16* __restrict__ Bt1, const u16* __restrict__ Bt2,
    int nsplit, void* __restrict__ Cv, int M, int N, int K, const int* __restrict__ sp) {
    __shared__ __align__(16) u16 As[128 * 32];
    __shared__ __align__(16) u16 Bs[128 * 32];
    const int tid = threadIdx.x;
    const int wave = tid >> 6, lane = tid & 63;
    const int quad = lane >> 4, l16 = lane & 15;
    const int bm = blockIdx.y * 128, bn = blockIdx.x * 128;
    const int wm = (wave >> 1) * 64, wn = (wave & 1) * 64;
    const int srow = wave * 32 + (lane >> 2);
    const int scol = (lane & 3) * 8;
    const u16* Bt = (bn < nsplit) ? (Bt1 + (size_t)bn * K)
                                  : (Bt2 + (size_t)(bn - nsplit) * K);

    float4v acc[4][4] = {};

    for (int k0 = 0; k0 < K; k0 += 32) {
        async16(A + (size_t)(bm + srow) * K + k0 + scol, (char*)As + wave * 2048);
        async16(A + (size_t)(bm + srow + 16) * K + k0 + scol, (char*)As + wave * 2048 + 1024);
        async16(Bt + (size_t)srow * K + k0 + scol, (char*)Bs + wave * 2048);
        async16(Bt + (size_t)(srow + 16) * K + k0 + scol, (char*)Bs + wave * 2048 + 1024);
        __syncthreads();
        short8 af[4], bf[4];
#pragma unroll
        for (int i = 0; i < 4; i++)
            af[i] = *(const short8*)(As + (wm + i * 16 + l16) * 32 + quad * 8);
#pragma unroll
        for (int j = 0; j < 4; j++)
            bf[j] = *(const short8*)(Bs + (wn + j * 16 + l16) * 32 + quad * 8);
#pragma unroll
        for (int i = 0; i < 4; i++)
#pragma unroll
            for (int j = 0; j < 4; j++)
                acc[i][j] = __builtin_amdgcn_mfma_f32_16x16x32_bf16(af[i], bf[j], acc[i][j], 0, 0, 0);
        __syncthreads();
    }
    const int sp0 = ROPE ? *sp : 0;
    // epilogue: C/D layout col=lane&15, row=quad*4+reg (m89/m91-verified).
#pragma unroll
    for (int j = 0; j < 4; j++) {
        int col = bn + wn + j * 16 + l16;
        bool do_rope = ROPE && (col < 2560);
        float inv = 0.f;
        if (do_rope) inv = __expf(-0.14391156816f * (float)((col & 127) >> 1));
#pragma unroll
        for (int i = 0; i < 4; i++) {
            int row0 = bm + wm + i * 16 + quad * 4;
#pragma unroll
            for (int r = 0; r < 4; r++) {
                float v = acc[i][j][r];
                if (do_rope) {
                    float partner = __shfl_xor(v, 1, 64);
                    float ang = (float)(sp0 + ((row0 + r) & (TT - 1))) * inv;
                    float c = __cosf(ang), s = __sinf(ang);
                    v = (col & 1) ? (partner * s + v * c)
                                  : (v * c - partner * s);
                }
                if (F32OUT) {
                    ((float*)Cv)[(size_t)(row0 + r) * N + col] = v;
                } else {
                    // packed QKV store (region is wave-uniform per j-block)
                    int rw = row0 + r;
                    int bb = rw >> 11, t = rw & 2047;
                    size_t addr;
                    if (col < 2048)
                        addr = QP_OFF + (size_t)(bb * 16 + (col >> 7)) * 262144
                             + (size_t)t * 128 + (col & 127);
                    else if (col < 2560)
                        addr = KP_OFF + (size_t)(bb * 4 + ((col - 2048) >> 7)) * 262144
                             + (size_t)t * 128 + (col & 127);
                    else
                        addr = VT_OFF + (size_t)(bb * 4 + ((col - 2560) >> 7)) * 262144
                             + (size_t)(col & 127) * 2048 + t;
                    ((u16*)Cv)[addr] = f2b(v);
                }
            }
        }
    }
}

// ---------------------------------------------------------------------------
// Flash attention v10: 256 threads = 4 waves, q-tile 128 rows, KVBLK=32.
// DIAGNOSIS (rounds 0-4): OccupancyPercent was always exactly HALF of the
// 2-blocks/CU prediction (25.7 vs 50, 12.4 vs 25, 12.2 vs 25) -> only ONE
// block per CU ever resident (every variant used >64KB LDS) -> 1 wave/SIMD,
// zero latency hiding -> all pipes idle, insensitive to traffic/conflicts.
// FIX: KVBLK 64->32: LDS = Ks 2x8K + Vs 2x8K + Ps 8K = 40,960 B -> 2 blocks
// truly co-resident (up to 4 allowed), 2 waves/SIMD, per-tile chain halves.
// Swizzles (4-chunk rows, XOR by (row>>1)&3; K rows unchanged ^(row&7)):
//   K  : LDS[kv][c] = K [kv][c ^ (kv&7)]        (16 chunks/row)
//   V^T: LDS[d][c]  = Vt[d][c ^ ((d>>1)&3)]     (4 chunks/row)
//   P  : LDS[rq][c] = P [rq][c ^ ((rq>>1)&3)]   (4 chunks/row)
// Balance map robust to BOTH candidate CU-pairings (jj^1 and jj^32):
//   h_lo=(b2,b0), u=(b4,b3,b1), p=b0^b5, qt = p ? 15-u : u  (bijective;
//   either pairing flips p only -> qt sum = 15 -> 68 kv-tiles per CU).
__global__ __launch_bounds__(256, 2) void attn_kernel(
    const u16* __restrict__ qkv, u16* __restrict__ y) {
    __shared__ __align__(16) u16 Ks[2][32 * 128];   // 2 x 8192 B
    __shared__ __align__(16) u16 Vs[2][128 * 32];   // 2 x 8192 B (V^T: d rows)
    __shared__ __align__(16) u16 Ps[4][32 * 32];    // 8192 B   (total 40960)

    const int tid = threadIdx.x;
    const int wave = tid >> 6, lane = tid & 63;
    const int quad = lane >> 4, l16 = lane & 15;
    const int bx = blockIdx.x;
    const int xg = bx & 7;             // XCD group = (b, hk)
    const int b = xg >> 2, hk = xg & 3;
    const int jj = bx >> 3;            // 0..63 within group = XCD stream pos
    // dual-pairing-robust balance map (see header comment)
    const int h = hk * 4 + 2 * ((jj >> 2) & 1) + (jj & 1);
    const int u = ((jj >> 1) & 1) | (((jj >> 3) & 1) << 1) | (((jj >> 4) & 1) << 2);
    const int p = ((jj >> 5) ^ jj) & 1;
    const int qt = p ? (15 - u) : u;
    const int g = b * 4 + hk;
    const float scale = 0.08838834764831845f;  // 1/sqrt(128)

    // Q fragments in registers (reused every kv-tile): 2 row-groups of 16
    const int wq0 = qt * 128 + wave * 32;
    const u16* qbase = qkv + QP_OFF + (size_t)(b * 16 + h) * 262144;
    short8 qf[2][4];
#pragma unroll
    for (int gi = 0; gi < 2; gi++) {
        const u16* qrow = qbase + (size_t)(wq0 + gi * 16 + l16) * 128;
#pragma unroll
        for (int d = 0; d < 4; d++)
            qf[gi][d] = *(const short8*)(qrow + d * 32 + quad * 8);
    }

    // Oacc[gi][0..7]: O tiles (2 x 16 x 128). Ol[gi]: row-sum l via ones MFMA.
    float4v Oacc[2][8] = {};
    float4v Ol[2] = {};
    const short8 ONES = {(short)0x3F80, (short)0x3F80, (short)0x3F80, (short)0x3F80,
                         (short)0x3F80, (short)0x3F80, (short)0x3F80, (short)0x3F80};

    const int ktmax = 4 * qt + 3;      // kv tiles - 1 (32 kv rows per tile)

    // K DMA source offsets (tile-relative; row stride 128 u16, 16 chunks/row).
    // Instr si covers LDS rows wave*8+si*4+quad, chunk l16; src chunk ^row&7.
    size_t kg[2];
#pragma unroll
    for (int si = 0; si < 2; si++) {
        int kr = wave * 8 + si * 4 + quad;
        kg[si] = (size_t)kr * 128 + (size_t)((l16 ^ (kr & 7)) * 8);
    }
    // V^T DMA source offsets (tile-relative; Vt row stride 2048 u16; LDS rows
    // = d, 4 chunks/row). Instr si covers d = wave*32+si*16+(lane>>2), chunk
    // lane&3; src chunk ^ (d>>1)&3  ( == (lane>>3)&3 here ).
    size_t vg[2];
#pragma unroll
    for (int si = 0; si < 2; si++) {
        int vr = wave * 32 + si * 16 + (lane >> 2);
        vg[si] = (size_t)vr * 2048 + (size_t)((((lane & 3) ^ ((lane >> 3) & 3)) * 8));
    }
    const u16* Kb = qkv + KP_OFF + (size_t)g * 262144;
    const u16* Vb = qkv + VT_OFF + (size_t)g * 262144;

    // kt=0 prefetch (both K and V^T via DMA)
#pragma unroll
    for (int si = 0; si < 2; si++)
        async16(Kb + kg[si], (char*)Ks[0] + wave * 2048 + si * 1024);
#pragma unroll
    for (int si = 0; si < 2; si++)
        async16(Vb + vg[si], (char*)Vs[0] + wave * 2048 + si * 1024);

    for (int kt = 0; kt <= ktmax; kt++) {
        const int cur = kt & 1;
        __syncthreads();   // vmcnt(0)+barrier: DMA for buf[cur] complete; all
                           // waves done reading buf[cur^1] from prev iter.
        if (kt < ktmax) {  // prefetch next tile into buf[cur^1]
#pragma unroll
            for (int si = 0; si < 2; si++)
                async16(Kb + (size_t)(kt + 1) * 4096 + kg[si],
                        (char*)Ks[cur ^ 1] + wave * 2048 + si * 1024);
#pragma unroll
            for (int si = 0; si < 2; si++)
                async16(Vb + (size_t)(kt + 1) * 32 + vg[si],
                        (char*)Vs[cur ^ 1] + wave * 2048 + si * 1024);
        }
        const u16* Kcur = Ks[cur];
        const u16* Vcur = Vs[cur];

        // S = Q*K^T  (K read through XOR swizzle; each K fragment feeds BOTH
        // q row-groups)
        float4v S[2][2] = {};
#pragma unroll
        for (int d = 0; d < 4; d++) {
#pragma unroll
            for (int j = 0; j < 2; j++) {
                short8 bk = *(const short8*)(Kcur + (j * 16 + l16) * 128
                                             + (((d * 4 + quad) ^ (l16 & 7)) * 8));
#pragma unroll
                for (int gi = 0; gi < 2; gi++)
                    S[gi][j] = __builtin_amdgcn_mfma_f32_16x16x32_bf16(qf[gi][d], bk, S[gi][j], 0, 0, 0);
            }
        }
        // P = exp(s*scale); causal mask -> 0.  Ps XOR-swizzled (4 chunks/row):
        // element (rq, kv=j*16+l16) -> chunk (j*2+(l16>>3)) ^ ((rq>>1)&3).
        const int kvb = kt * 32 + l16;
        const bool diag = (kt * 32 + 31 > wq0);
#pragma unroll
        for (int gi = 0; gi < 2; gi++) {
            const int qbq = wq0 + gi * 16 + quad * 4;
#pragma unroll
            for (int j = 0; j < 2; j++)
#pragma unroll
                for (int r = 0; r < 4; r++) {
                    bool masked = diag && (kvb + j * 16 > qbq + r);
                    float pv = masked ? 0.f : __expf(S[gi][j][r] * scale);
                    int rq = gi * 16 + quad * 4 + r;
                    int ch = (j * 2 + (l16 >> 3)) ^ ((rq >> 1) & 3);
                    Ps[wave][rq * 32 + ch * 8 + (l16 & 7)] = f2b(pv);
                }
        }
        // per-wave LDS RAW fence before cross-lane reads of Ps[wave]
        __asm__ volatile("s_waitcnt lgkmcnt(0)" ::: "memory");
        // O += P(32x32) @ V(32x128); l += P @ ones
        short8 ap[2];
#pragma unroll
        for (int gi = 0; gi < 2; gi++) {
            int rq = gi * 16 + l16;
            ap[gi] = *(const short8*)(Ps[wave] + rq * 32
                                      + ((quad ^ ((l16 >> 1) & 3)) * 8));
        }
#pragma unroll
        for (int dt = 0; dt < 8; dt++) {
            short8 bv = *(const short8*)(Vcur + (dt * 16 + l16) * 32
                                         + ((quad ^ ((l16 >> 1) & 3)) * 8));
#pragma unroll
            for (int gi = 0; gi < 2; gi++)
                Oacc[gi][dt] = __builtin_amdgcn_mfma_f32_16x16x32_bf16(ap[gi], bv, Oacc[gi][dt], 0, 0, 0);
        }
#pragma unroll
        for (int gi = 0; gi < 2; gi++)
            Ol[gi] = __builtin_amdgcn_mfma_f32_16x16x32_bf16(ap[gi], ONES, Ol[gi], 0, 0, 0);
    }
    // epilogue: y bf16 [b*T + q][h*128 + d]; normalize by l = Ol[gi]
#pragma unroll
    for (int gi = 0; gi < 2; gi++)
#pragma unroll
        for (int dt = 0; dt < 8; dt++)
#pragma unroll
            for (int r = 0; r < 4; r++) {
                float v = Oacc[gi][dt][r] / Ol[gi][r];
                y[(size_t)(b * TT + wq0 + gi * 16 + quad * 4 + r) * D_MODEL
                  + h * 128 + dt * 16 + l16] = f2b(v);
            }
}

// ---------------------------------------------------------------------------
// Memory plan (ws use = 25,165,824 B, proven available; inputs/out fp32):
//   ws[0, 16.78M):      xb (phases 1-4) -> Y (attn -> gemm2)
//   ws[16.78M, 25.17M): WqkvT rows 0..2047 (gemm1) -> WoT (gemm2)
//   d_out[0, 25.17M):   packed Qp/Kp/Vt bf16 (gemm1 -> attn) -> final fp32 out
//   d_out[25.17M, 33.55M): WqkvT rows 2048..3071 (gemm1 only; dead after)
extern "C" void kernel_launch(void* const* d_in, const int* in_sizes, int n_in,
                              void* d_out, int out_size, void* d_ws, size_t ws_size,
                              hipStream_t stream) {
    const float* x    = (const float*)d_in[0];   // 4096 x 2048 fp32
    const float* Wqkv = (const float*)d_in[1];   // 2048 x 3072 fp32
    const float* Wo   = (const float*)d_in[2];   // 2048 x 2048 fp32
    const int*   sp   = (const int*)d_in[3];

    char* ws = (char*)d_ws;
    char* dob = (char*)d_out;
    u16*   xb     = (u16*)ws;                    // 4096x2048 bf16
    u16*   Y      = (u16*)ws;                    //    (after gemm1: attn output)
    u16*   WqkvTA = (u16*)(ws + 16777216);       // N-rows 0..2047 of Wqkv^T
    u16*   WoT    = (u16*)(ws + 16777216);       //    (after gemm1)
    u16*   QKVp   = (u16*)d_out;                 // packed Qp/Kp/Vt bf16
    u16*   WqkvTB = (u16*)(dob + 25165824);      // N-rows 2048..3071 of Wqkv^T
    float* out    = (float*)d_out;

    // 1. x -> bf16
    convert_f2b<<<ROWS * D_MODEL / 4 / 256, 256, 0, stream>>>(x, xb);
    // 2. Wqkv^T split across the two scratch tails
    transpose_f2b<<<dim3(64, 64), 256, 0, stream>>>(Wqkv, WqkvTA, D_MODEL, QKV_DIM, 0);
    transpose_f2b<<<dim3(32, 64), 256, 0, stream>>>(Wqkv, WqkvTB, D_MODEL, QKV_DIM, 2048);
    // 3. packed QKV = x @ Wqkv with fused RoPE (async m97 structure, fast trig)
    gemm_bt_async<false, true><<<dim3(QKV_DIM / 128, ROWS / 128), 256, 0, stream>>>(
        xb, WqkvTA, WqkvTB, 2048, QKVp, ROWS, QKV_DIM, D_MODEL, sp);
    // 4. Wo^T (overwrites WqkvTA, dead)
    transpose_f2b<<<dim3(64, 64), 256, 0, stream>>>(Wo, WoT, D_MODEL, D_MODEL, 0);
    // 5. flash attention -> Y (overwrites xb, dead)
    attn_kernel<<<512, 256, 0, stream>>>(QKVp, Y);
    // 6. out = Y @ Wo -> fp32 (overwrites packed QKV + WqkvTB, dead)
    gemm_bt_async<true, false><<<dim3(D_MODEL / 128, ROWS / 128), 256, 0, stream>>>(
        Y, WoT, WoT, D_MODEL, out, ROWS, D_MODEL, D_MODEL, sp);
}

// Round 6
// 331.599 us; speedup vs baseline: 1.0674x; 1.0371x over previous
//
#include <hip/hip_runtime.h>
#include <math.h>

// Problem constants
#define D_MODEL 2048
#define N_HEADS 16
#define N_KV    4
#define DH      128
#define QKV_DIM 3072   // 2048 + 2*4*128
#define TT      2048   // T
#define BB      2      // B
#define ROWS    (BB*TT)  // 4096

// Packed QKV layout in d_out (u16 offsets). Written by gemm1 epilogue:
//   Qp[b][h][t][d]   : ((b*16+h)*2048 + t)*128 + d          @ 0
//   Kp[g][t][d]      : (g*2048 + t)*128 + d                 @ 8,388,608   (g=b*4+hk)
//   Vt[g][d][t]      : (g*128 + d)*2048 + t                 @ 10,485,760  (V pre-transposed)
// Total 12,582,912 u16 = 25,165,824 B (same region/lifetime as old QKV).
#define QP_OFF 0u
#define KP_OFF 8388608u
#define VT_OFF 10485760u

typedef unsigned short u16;
typedef short short8 __attribute__((ext_vector_type(8)));
typedef short short4v __attribute__((ext_vector_type(4)));
typedef float float4v __attribute__((ext_vector_type(4)));

__device__ inline u16 f2b(float f) {
    union { float f; unsigned u; } v; v.f = f;
    unsigned r = v.u + 0x7FFF + ((v.u >> 16) & 1);
    return (u16)(r >> 16);
}

// async global->LDS DMA, 16 bytes/lane. LDS dest = wave-uniform base + lane*16.
__device__ inline void async16(const void* g, void* l) {
    __builtin_amdgcn_global_load_lds(
        (const __attribute__((address_space(1))) void*)g,
        (__attribute__((address_space(3))) void*)l, 16, 0, 0);
}

// ---------------------------------------------------------------------------
// 32x32 transpose tile body (shared by prep/attn_wo fused kernels).
// dst[c][r] = bf16(src[r][c + col0]). 256 threads. tile = u16[32][33].
__device__ inline void transpose_tile(const float* __restrict__ src,
                                      u16* __restrict__ dst,
                                      int R, int C, int col0,
                                      int bx, int by, u16* tile) {
    int bc = bx * 32, br = by * 32;
    int tx = threadIdx.x & 31, ty = threadIdx.x >> 5;   // ty 0..7
    for (int i = ty; i < 32; i += 8)
        tile[i * 33 + tx] = f2b(src[(size_t)(br + i) * C + col0 + bc + tx]);
    __syncthreads();
    for (int i = ty; i < 32; i += 8)
        dst[(size_t)(bc + i) * R + br + tx] = tile[tx * 33 + i];
}

// ---------------------------------------------------------------------------
// Fused preprocessing (saves 2 launch gaps):
//   blocks [0, 8192)        : x fp32 -> xb bf16 (vectorized convert)
//   blocks [8192, 12288)    : Wqkv^T cols 0..2047  -> WqkvTA
//   blocks [12288, 14336)   : Wqkv^T cols 2048..3071 -> WqkvTB
__global__ __launch_bounds__(256) void prep_kernel(
    const float* __restrict__ x, u16* __restrict__ xb,
    const float* __restrict__ Wqkv, u16* __restrict__ WA, u16* __restrict__ WB) {
    __shared__ __align__(16) u16 tile[32 * 33];
    int bid = blockIdx.x;
    if (bid < 8192) {
        size_t i = (size_t)bid * 256 + threadIdx.x;
        float4v a = *(const float4v*)(x + i * 4);
        short4v p;
        p[0] = (short)f2b(a[0]); p[1] = (short)f2b(a[1]);
        p[2] = (short)f2b(a[2]); p[3] = (short)f2b(a[3]);
        *(short4v*)(xb + i * 4) = p;
    } else if (bid < 12288) {
        int t = bid - 8192;                     // dim3(64,64)
        transpose_tile(Wqkv, WA, D_MODEL, QKV_DIM, 0, t & 63, t >> 6, tile);
    } else {
        int t = bid - 12288;                    // dim3(32,64)
        transpose_tile(Wqkv, WB, D_MODEL, QKV_DIM, 2048, t & 31, t >> 5, tile);
    }
}

// ---------------------------------------------------------------------------
// m97-style async GEMM: C[M,N] = A[M,K] @ Bt[N,K]^T, bf16 in, fp32 accum.
// B^T split across two buffers at N-row `nsplit` (workspace tetris).
// ROPE: fused rotary on cols < 2560 (fast hw trig: __sinf/__cosf/__expf).
// !F32OUT (gemm1): writes the PACKED QKV layout (Qp/Kp/Vt) — per-element
// stores anyway, so the remap is free; V is written pre-transposed so attn
// can DMA V^T tiles linearly instead of a 64-line scatter-gather.
template<bool F32OUT, bool ROPE>
__global__ __launch_bounds__(256) void gemm_bt_async(
    const u16* __restrict__ A, const u16* __restrict__ Bt1, const u16* __restrict__ Bt2,
    int nsplit, void* __restrict__ Cv, int M, int N, int K, const int* __restrict__ sp) {
    __shared__ __align__(16) u16 As[128 * 32];
    __shared__ __align__(16) u16 Bs[128 * 32];
    const int tid = threadIdx.x;
    const int wave = tid >> 6, lane = tid & 63;
    const int quad = lane >> 4, l16 = lane & 15;
    const int bm = blockIdx.y * 128, bn = blockIdx.x * 128;
    const int wm = (wave >> 1) * 64, wn = (wave & 1) * 64;
    const int srow = wave * 32 + (lane >> 2);
    const int scol = (lane & 3) * 8;
    const u16* Bt = (bn < nsplit) ? (Bt1 + (size_t)bn * K)
                                  : (Bt2 + (size_t)(bn - nsplit) * K);

    float4v acc[4][4] = {};

    for (int k0 = 0; k0 < K; k0 += 32) {
        async16(A + (size_t)(bm + srow) * K + k0 + scol, (char*)As + wave * 2048);
        async16(A + (size_t)(bm + srow + 16) * K + k0 + scol, (char*)As + wave * 2048 + 1024);
        async16(Bt + (size_t)srow * K + k0 + scol, (char*)Bs + wave * 2048);
        async16(Bt + (size_t)(srow + 16) * K + k0 + scol, (char*)Bs + wave * 2048 + 1024);
        __syncthreads();
        short8 af[4], bf[4];
#pragma unroll
        for (int i = 0; i < 4; i++)
            af[i] = *(const short8*)(As + (wm + i * 16 + l16) * 32 + quad * 8);
#pragma unroll
        for (int j = 0; j < 4; j++)
            bf[j] = *(const short8*)(Bs + (wn + j * 16 + l16) * 32 + quad * 8);
#pragma unroll
        for (int i = 0; i < 4; i++)
#pragma unroll
            for (int j = 0; j < 4; j++)
                acc[i][j] = __builtin_amdgcn_mfma_f32_16x16x32_bf16(af[i], bf[j], acc[i][j], 0, 0, 0);
        __syncthreads();
    }
    const int sp0 = ROPE ? *sp : 0;
    // epilogue: C/D layout col=lane&15, row=quad*4+reg (m89/m91-verified).
#pragma unroll
    for (int j = 0; j < 4; j++) {
        int col = bn + wn + j * 16 + l16;
        bool do_rope = ROPE && (col < 2560);
        float inv = 0.f;
        if (do_rope) inv = __expf(-0.14391156816f * (float)((col & 127) >> 1));
#pragma unroll
        for (int i = 0; i < 4; i++) {
            int row0 = bm + wm + i * 16 + quad * 4;
#pragma unroll
            for (int r = 0; r < 4; r++) {
                float v = acc[i][j][r];
                if (do_rope) {
                    float partner = __shfl_xor(v, 1, 64);
                    float ang = (float)(sp0 + ((row0 + r) & (TT - 1))) * inv;
                    float c = __cosf(ang), s = __sinf(ang);
                    v = (col & 1) ? (partner * s + v * c)
                                  : (v * c - partner * s);
                }
                if (F32OUT) {
                    ((float*)Cv)[(size_t)(row0 + r) * N + col] = v;
                } else {
                    // packed QKV store (region is wave-uniform per j-block)
                    int rw = row0 + r;
                    int bb = rw >> 11, t = rw & 2047;
                    size_t addr;
                    if (col < 2048)
                        addr = QP_OFF + (size_t)(bb * 16 + (col >> 7)) * 262144
                             + (size_t)t * 128 + (col & 127);
                    else if (col < 2560)
                        addr = KP_OFF + (size_t)(bb * 4 + ((col - 2048) >> 7)) * 262144
                             + (size_t)t * 128 + (col & 127);
                    else
                        addr = VT_OFF + (size_t)(bb * 4 + ((col - 2560) >> 7)) * 262144
                             + (size_t)(col & 127) * 2048 + t;
                    ((u16*)Cv)[addr] = f2b(v);
                }
            }
        }
    }
}

// ---------------------------------------------------------------------------
// Fused flash-attention + Wo^T transpose (saves 1 launch gap; the 4096
// transpose blocks backfill spare LDS/VGPR alongside attn's 2 blocks/CU and
// run inside attn's ~96%-idle memory pipes).
//   blocks [0, 512)     : flash attention v10 (unchanged from round 5)
//   blocks [512, 4608)  : Wo^T transpose -> WoT (reads Wo, writes dead
//                         WqkvTA region; fully disjoint from attn's R/W sets)
__global__ __launch_bounds__(256, 2) void attn_wo_kernel(
    const u16* __restrict__ qkv, u16* __restrict__ y,
    const float* __restrict__ Wo, u16* __restrict__ WoT) {
    __shared__ __align__(16) u16 Ks[2][32 * 128];   // 2 x 8192 B
    __shared__ __align__(16) u16 Vs[2][128 * 32];   // 2 x 8192 B (V^T: d rows)
    __shared__ __align__(16) u16 Ps[4][32 * 32];    // 8192 B   (total 40960)

    if (blockIdx.x >= 512) {                        // Wo^T transpose blocks
        int t = blockIdx.x - 512;                   // dim3(64,64)
        transpose_tile(Wo, WoT, D_MODEL, D_MODEL, 0, t & 63, t >> 6, (u16*)Ks[0]);
        return;
    }

    const int tid = threadIdx.x;
    const int wave = tid >> 6, lane = tid & 63;
    const int quad = lane >> 4, l16 = lane & 15;
    const int bx = blockIdx.x;
    const int xg = bx & 7;             // XCD group = (b, hk)
    const int b = xg >> 2, hk = xg & 3;
    const int jj = bx >> 3;            // 0..63 within group = XCD stream pos
    // dual-pairing-robust balance map (jj^1 and jj^32 both flip parity only)
    const int h = hk * 4 + 2 * ((jj >> 2) & 1) + (jj & 1);
    const int u = ((jj >> 1) & 1) | (((jj >> 3) & 1) << 1) | (((jj >> 4) & 1) << 2);
    const int p = ((jj >> 5) ^ jj) & 1;
    const int qt = p ? (15 - u) : u;
    const int g = b * 4 + hk;
    const float scale = 0.08838834764831845f;  // 1/sqrt(128)

    // Q fragments in registers (reused every kv-tile): 2 row-groups of 16
    const int wq0 = qt * 128 + wave * 32;
    const u16* qbase = qkv + QP_OFF + (size_t)(b * 16 + h) * 262144;
    short8 qf[2][4];
#pragma unroll
    for (int gi = 0; gi < 2; gi++) {
        const u16* qrow = qbase + (size_t)(wq0 + gi * 16 + l16) * 128;
#pragma unroll
        for (int d = 0; d < 4; d++)
            qf[gi][d] = *(const short8*)(qrow + d * 32 + quad * 8);
    }

    // Oacc[gi][0..7]: O tiles (2 x 16 x 128). Ol[gi]: row-sum l via ones MFMA.
    float4v Oacc[2][8] = {};
    float4v Ol[2] = {};
    const short8 ONES = {(short)0x3F80, (short)0x3F80, (short)0x3F80, (short)0x3F80,
                         (short)0x3F80, (short)0x3F80, (short)0x3F80, (short)0x3F80};

    const int ktmax = 4 * qt + 3;      // kv tiles - 1 (32 kv rows per tile)

    // K DMA source offsets (tile-relative; row stride 128 u16, 16 chunks/row).
    // Instr si covers LDS rows wave*8+si*4+quad, chunk l16; src chunk ^row&7.
    size_t kg[2];
#pragma unroll
    for (int si = 0; si < 2; si++) {
        int kr = wave * 8 + si * 4 + quad;
        kg[si] = (size_t)kr * 128 + (size_t)((l16 ^ (kr & 7)) * 8);
    }
    // V^T DMA source offsets (tile-relative; Vt row stride 2048 u16; LDS rows
    // = d, 4 chunks/row). Instr si covers d = wave*32+si*16+(lane>>2), chunk
    // lane&3; src chunk ^ (d>>1)&3  ( == (lane>>3)&3 here ).
    size_t vg[2];
#pragma unroll
    for (int si = 0; si < 2; si++) {
        int vr = wave * 32 + si * 16 + (lane >> 2);
        vg[si] = (size_t)vr * 2048 + (size_t)((((lane & 3) ^ ((lane >> 3) & 3)) * 8));
    }
    const u16* Kb = qkv + KP_OFF + (size_t)g * 262144;
    const u16* Vb = qkv + VT_OFF + (size_t)g * 262144;

    // kt=0 prefetch (both K and V^T via DMA)
#pragma unroll
    for (int si = 0; si < 2; si++)
        async16(Kb + kg[si], (char*)Ks[0] + wave * 2048 + si * 1024);
#pragma unroll
    for (int si = 0; si < 2; si++)
        async16(Vb + vg[si], (char*)Vs[0] + wave * 2048 + si * 1024);

    for (int kt = 0; kt <= ktmax; kt++) {
        const int cur = kt & 1;
        __syncthreads();   // vmcnt(0)+barrier: DMA for buf[cur] complete; all
                           // waves done reading buf[cur^1] from prev iter.
        if (kt < ktmax) {  // prefetch next tile into buf[cur^1]
#pragma unroll
            for (int si = 0; si < 2; si++)
                async16(Kb + (size_t)(kt + 1) * 4096 + kg[si],
                        (char*)Ks[cur ^ 1] + wave * 2048 + si * 1024);
#pragma unroll
            for (int si = 0; si < 2; si++)
                async16(Vb + (size_t)(kt + 1) * 32 + vg[si],
                        (char*)Vs[cur ^ 1] + wave * 2048 + si * 1024);
        }
        const u16* Kcur = Ks[cur];
        const u16* Vcur = Vs[cur];

        // S = Q*K^T  (K read through XOR swizzle; each K fragment feeds BOTH
        // q row-groups)
        float4v S[2][2] = {};
#pragma unroll
        for (int d = 0; d < 4; d++) {
#pragma unroll
            for (int j = 0; j < 2; j++) {
                short8 bk = *(const short8*)(Kcur + (j * 16 + l16) * 128
                                             + (((d * 4 + quad) ^ (l16 & 7)) * 8));
#pragma unroll
                for (int gi = 0; gi < 2; gi++)
                    S[gi][j] = __builtin_amdgcn_mfma_f32_16x16x32_bf16(qf[gi][d], bk, S[gi][j], 0, 0, 0);
            }
        }
        // P = exp(s*scale); causal mask -> 0.  Ps XOR-swizzled (4 chunks/row):
        // element (rq, kv=j*16+l16) -> chunk (j*2+(l16>>3)) ^ ((rq>>1)&3).
        const int kvb = kt * 32 + l16;
        const bool diag = (kt * 32 + 31 > wq0);
#pragma unroll
        for (int gi = 0; gi < 2; gi++) {
            const int qbq = wq0 + gi * 16 + quad * 4;
#pragma unroll
            for (int j = 0; j < 2; j++)
#pragma unroll
                for (int r = 0; r < 4; r++) {
                    bool masked = diag && (kvb + j * 16 > qbq + r);
                    float pv = masked ? 0.f : __expf(S[gi][j][r] * scale);
                    int rq = gi * 16 + quad * 4 + r;
                    int ch = (j * 2 + (l16 >> 3)) ^ ((rq >> 1) & 3);
                    Ps[wave][rq * 32 + ch * 8 + (l16 & 7)] = f2b(pv);
                }
        }
        // per-wave LDS RAW fence before cross-lane reads of Ps[wave]
        __asm__ volatile("s_waitcnt lgkmcnt(0)" ::: "memory");
        // O += P(32x32) @ V(32x128); l += P @ ones
        short8 ap[2];
#pragma unroll
        for (int gi = 0; gi < 2; gi++) {
            int rq = gi * 16 + l16;
            ap[gi] = *(const short8*)(Ps[wave] + rq * 32
                                      + ((quad ^ ((l16 >> 1) & 3)) * 8));
        }
#pragma unroll
        for (int dt = 0; dt < 8; dt++) {
            short8 bv = *(const short8*)(Vcur + (dt * 16 + l16) * 32
                                         + ((quad ^ ((l16 >> 1) & 3)) * 8));
#pragma unroll
            for (int gi = 0; gi < 2; gi++)
                Oacc[gi][dt] = __builtin_amdgcn_mfma_f32_16x16x32_bf16(ap[gi], bv, Oacc[gi][dt], 0, 0, 0);
        }
#pragma unroll
        for (int gi = 0; gi < 2; gi++)
            Ol[gi] = __builtin_amdgcn_mfma_f32_16x16x32_bf16(ap[gi], ONES, Ol[gi], 0, 0, 0);
    }
    // epilogue: y bf16 [b*T + q][h*128 + d]; normalize by l = Ol[gi]
#pragma unroll
    for (int gi = 0; gi < 2; gi++)
#pragma unroll
        for (int dt = 0; dt < 8; dt++)
#pragma unroll
            for (int r = 0; r < 4; r++) {
                float v = Oacc[gi][dt][r] / Ol[gi][r];
                y[(size_t)(b * TT + wq0 + gi * 16 + quad * 4 + r) * D_MODEL
                  + h * 128 + dt * 16 + l16] = f2b(v);
            }
}

// ---------------------------------------------------------------------------
// Memory plan (ws use = 25,165,824 B, proven available; inputs/out fp32):
//   ws[0, 16.78M):      xb (phases 1-2) -> Y (attn -> gemm2)
//   ws[16.78M, 25.17M): WqkvT rows 0..2047 (gemm1) -> WoT (gemm2)
//   d_out[0, 25.17M):   packed Qp/Kp/Vt bf16 (gemm1 -> attn) -> final fp32 out
//   d_out[25.17M, 33.55M): WqkvT rows 2048..3071 (gemm1 only; dead after)
// Launches: 4 (was 7) — prep, gemm1, attn+WoT, gemm2.
extern "C" void kernel_launch(void* const* d_in, const int* in_sizes, int n_in,
                              void* d_out, int out_size, void* d_ws, size_t ws_size,
                              hipStream_t stream) {
    const float* x    = (const float*)d_in[0];   // 4096 x 2048 fp32
    const float* Wqkv = (const float*)d_in[1];   // 2048 x 3072 fp32
    const float* Wo   = (const float*)d_in[2];   // 2048 x 2048 fp32
    const int*   sp   = (const int*)d_in[3];

    char* ws = (char*)d_ws;
    char* dob = (char*)d_out;
    u16*   xb     = (u16*)ws;                    // 4096x2048 bf16
    u16*   Y      = (u16*)ws;                    //    (after gemm1: attn output)
    u16*   WqkvTA = (u16*)(ws + 16777216);       // N-rows 0..2047 of Wqkv^T
    u16*   WoT    = (u16*)(ws + 16777216);       //    (after gemm1)
    u16*   QKVp   = (u16*)d_out;                 // packed Qp/Kp/Vt bf16
    u16*   WqkvTB = (u16*)(dob + 25165824);      // N-rows 2048..3071 of Wqkv^T
    float* out    = (float*)d_out;

    // 1. fused prep: x->bf16 + Wqkv^T (both halves)
    prep_kernel<<<14336, 256, 0, stream>>>(x, xb, Wqkv, WqkvTA, WqkvTB);
    // 2. packed QKV = x @ Wqkv with fused RoPE (async m97 structure, fast trig)
    gemm_bt_async<false, true><<<dim3(QKV_DIM / 128, ROWS / 128), 256, 0, stream>>>(
        xb, WqkvTA, WqkvTB, 2048, QKVp, ROWS, QKV_DIM, D_MODEL, sp);
    // 3. fused flash attention (-> Y, overwrites xb) + Wo^T (-> dead WqkvTA)
    attn_wo_kernel<<<4608, 256, 0, stream>>>(QKVp, Y, Wo, WoT);
    // 4. out = Y @ Wo -> fp32 (overwrites packed QKV + WqkvTB, dead)
    gemm_bt_async<true, false><<<dim3(D_MODEL / 128, ROWS / 128), 256, 0, stream>>>(
        Y, WoT, WoT, D_MODEL, out, ROWS, D_MODEL, D_MODEL, sp);
}